// Round 11
// baseline (309.948 us; speedup 1.0000x reference)
//
#include <hip/hip_runtime.h>

#define E_EDGES 640000
#define NN 10000
#define HID 32
#define EDIM 128
#define CH 50      // GRU steps per LDS chunk
#define CCH 50     // output steps per scan block
#define WARM 100   // warmup steps (multiple of CH)
#define NBLK 200   // NN / CCH

typedef _Float16 f16;
typedef _Float16 f16x8 __attribute__((ext_vector_type(8)));
typedef _Float16 f16x2 __attribute__((ext_vector_type(2)));
typedef float f32x4 __attribute__((ext_vector_type(4)));

static __device__ __forceinline__ f16x2 pkrtz(float a, float b) {
  auto t = __builtin_amdgcn_cvt_pkrtz(a, b);
  f16x2 r;
  __builtin_memcpy(&r, &t, 4);
  return r;
}

static __device__ __forceinline__ f16x8 cvt8(float4 a, float4 b) {
  auto p0 = __builtin_amdgcn_cvt_pkrtz(a.x, a.y);
  auto p1 = __builtin_amdgcn_cvt_pkrtz(a.z, a.w);
  auto p2 = __builtin_amdgcn_cvt_pkrtz(b.x, b.y);
  auto p3 = __builtin_amdgcn_cvt_pkrtz(b.z, b.w);
  f16x8 r;
  __builtin_memcpy((char*)&r,      &p0, 4);
  __builtin_memcpy((char*)&r + 4,  &p1, 4);
  __builtin_memcpy((char*)&r + 8,  &p2, 4);
  __builtin_memcpy((char*)&r + 12, &p3, 4);
  return r;
}

static __device__ __forceinline__ f16x8 splat8(float h) {
  auto p = __builtin_amdgcn_cvt_pkrtz(h, h);
  int si;
  __builtin_memcpy(&si, &p, 4);
  int v[4] = {si, si, si, si};
  f16x8 r;
  __builtin_memcpy(&r, v, 16);
  return r;
}

// ---------------- prep: zero cnt, build f16 fragment-ordered weights ----------------
__global__ __launch_bounds__(256) void prep_kernel(
    const float* __restrict__ w1, const float* __restrict__ w2,
    const float* __restrict__ b2, int* __restrict__ cnt,
    f16* __restrict__ Wf, f16* __restrict__ W1f)
{
  int tid = blockIdx.x * 256 + threadIdx.x;
  if (tid < NN) cnt[tid] = 0;
  if (tid < 33 * 1024) {
    int r = tid & 7, l = (tid >> 3) & 63, h = (tid >> 9) & 1, c2 = tid >> 10;
    int i = (l & 15) + 16 * h, j = (l >> 4) * 8 + r;
    float v = (c2 < 32) ? w2[c2 * 1024 + i * 32 + j] : b2[i * 32 + j];
    Wf[tid] = (f16)v;
  }
  if (tid < 4 * 1024) {
    int r = tid & 7, l = (tid >> 3) & 63, h = (tid >> 9) & 1, c = tid >> 10;
    int d = c * 32 + (l >> 4) * 8 + r, k = (l & 15) + 16 * h;
    W1f[tid] = (f16)w1[d * 32 + k];
  }
}

// ---------------- CSR build ----------------
__global__ __launch_bounds__(256) void hist_kernel(
    const int* __restrict__ ei, int* __restrict__ cnt)
{
  int tid = blockIdx.x * 256 + threadIdx.x;
  if (tid < E_EDGES) atomicAdd(&cnt[ei[tid]], 1);
}

__global__ __launch_bounds__(256) void scan_kernel(
    const int* __restrict__ cnt, int* __restrict__ row_ptr, int* __restrict__ ofs)
{
  __shared__ int tot[256];
  int t = threadIdx.x;
  int base = t * 40;
  int s = 0;
  for (int i = 0; i < 40; ++i) {
    int idx = base + i;
    if (idx < NN) s += cnt[idx];
  }
  tot[t] = s;
  __syncthreads();
  for (int off = 1; off < 256; off <<= 1) {
    int v = (t >= off) ? tot[t - off] : 0;
    __syncthreads();
    tot[t] += v;
    __syncthreads();
  }
  int running = (t == 0) ? 0 : tot[t - 1];
  for (int i = 0; i < 40; ++i) {
    int idx = base + i;
    if (idx < NN) {
      row_ptr[idx] = running;
      ofs[idx] = running;
      running += cnt[idx];
    }
  }
  if (t == 255) row_ptr[NN] = tot[255];
}

__global__ __launch_bounds__(256) void fill_kernel(
    const int* __restrict__ ei, int* __restrict__ ofs, int* __restrict__ eid)
{
  int tid = blockIdx.x * 256 + threadIdx.x;
  if (tid < E_EDGES) {
    int r = ei[tid];
    int p = atomicAdd(&ofs[r], 1);
    eid[p] = tid;
  }
}

// ---------------- edges: sorted slots, dense msg store, NO atomics ----------------
__global__ __launch_bounds__(256) void edges_kernel(
    const float* __restrict__ x, const int* __restrict__ ei,
    const float* __restrict__ ea, const float* __restrict__ b1,
    const f16* __restrict__ Wf, const f16* __restrict__ W1f,
    const int* __restrict__ eid, float* __restrict__ msg)
{
  __shared__ float h1s[4][64][36];
  int t = threadIdx.x;
  int wave = t >> 6, l = t & 63;
  int base = (blockIdx.x * 4 + wave) * 64;
  const int* colp = ei + E_EDGES;
  int m16 = l & 15, g4 = l >> 4;

  // per-lane edge ids for the 4 sub-tiles (slot -> edge indirection)
  int ew[4];
  #pragma unroll
  for (int tt = 0; tt < 4; ++tt) ew[tt] = eid[base + tt * 16 + m16];

  // direct per-lane x gather (x is L2/L3-resident)
  f16x8 nv[4];
  #pragma unroll
  for (int tt = 0; tt < 4; ++tt) {
    int c = colp[ew[tt]];
    const float* xr = x + (long)c * HID + g4 * 8;
    nv[tt] = cvt8(*(const float4*)xr, *(const float4*)(xr + 4));
  }

  // GEMM1: h1 = relu(EA @ W1 + b1), 4 sub-tiles share each B-read
  f32x4 acc[4][2];
  #pragma unroll
  for (int tt = 0; tt < 4; ++tt) { acc[tt][0] = {0.f,0.f,0.f,0.f}; acc[tt][1] = {0.f,0.f,0.f,0.f}; }
  #pragma unroll
  for (int c = 0; c < 4; ++c) {
    f16x8 A[4];
    #pragma unroll
    for (int tt = 0; tt < 4; ++tt) {
      const float* eb = ea + (long)ew[tt] * EDIM + g4 * 8 + c * 32;
      A[tt] = cvt8(*(const float4*)eb, *(const float4*)(eb + 4));
    }
    f16x8 b0  = *(const f16x8*)(W1f + ((c * 2 + 0) * 64 + l) * 8);
    f16x8 b1v = *(const f16x8*)(W1f + ((c * 2 + 1) * 64 + l) * 8);
    #pragma unroll
    for (int tt = 0; tt < 4; ++tt) {
      acc[tt][0] = __builtin_amdgcn_mfma_f32_16x16x32_f16(A[tt], b0,  acc[tt][0], 0, 0, 0);
      acc[tt][1] = __builtin_amdgcn_mfma_f32_16x16x32_f16(A[tt], b1v, acc[tt][1], 0, 0, 0);
    }
  }
  float bb0 = b1[m16], bb1 = b1[m16 + 16];
  #pragma unroll
  for (int tt = 0; tt < 4; ++tt) {
    #pragma unroll
    for (int r = 0; r < 4; ++r) {
      h1s[wave][tt * 16 + g4 * 4 + r][m16]      = fmaxf(acc[tt][0][r] + bb0, 0.f);
      h1s[wave][tt * 16 + g4 * 4 + r][m16 + 16] = fmaxf(acc[tt][1][r] + bb1, 0.f);
    }
  }
  if (m16 == 0) {
    #pragma unroll
    for (int tt = 0; tt < 4; ++tt)
      #pragma unroll
      for (int r = 0; r < 4; ++r) h1s[wave][tt * 16 + g4 * 4 + r][32] = 1.f;
  }
  asm volatile("s_waitcnt lgkmcnt(0)" ::: "memory");   // LDS wave-private

  // GEMM2: messages = Z @ W
  f32x4 mc[4][2];
  #pragma unroll
  for (int tt = 0; tt < 4; ++tt) { mc[tt][0] = {0.f,0.f,0.f,0.f}; mc[tt][1] = {0.f,0.f,0.f,0.f}; }

  #pragma unroll
  for (int cb = 0; cb < 8; ++cb) {
    float4 hv[4];
    #pragma unroll
    for (int tt = 0; tt < 4; ++tt)
      hv[tt] = *(const float4*)(&h1s[wave][tt * 16 + m16][cb * 4]);
    #pragma unroll
    for (int q = 0; q < 4; ++q) {
      int c2 = cb * 4 + q;
      f16x8 B0 = *(const f16x8*)(Wf + ((c2 * 2 + 0) * 64 + l) * 8);
      f16x8 B1 = *(const f16x8*)(Wf + ((c2 * 2 + 1) * 64 + l) * 8);
      #pragma unroll
      for (int tt = 0; tt < 4; ++tt) {
        float hf = (q == 0) ? hv[tt].x : (q == 1) ? hv[tt].y : (q == 2) ? hv[tt].z : hv[tt].w;
        f16x8 A = nv[tt] * splat8(hf);
        mc[tt][0] = __builtin_amdgcn_mfma_f32_16x16x32_f16(A, B0, mc[tt][0], 0, 0, 0);
        mc[tt][1] = __builtin_amdgcn_mfma_f32_16x16x32_f16(A, B1, mc[tt][1], 0, 0, 0);
      }
    }
  }
  { // c2 = 32: ones-row (b2 folded into Wf)
    f16x8 B0 = *(const f16x8*)(Wf + ((32 * 2 + 0) * 64 + l) * 8);
    f16x8 B1 = *(const f16x8*)(Wf + ((32 * 2 + 1) * 64 + l) * 8);
    #pragma unroll
    for (int tt = 0; tt < 4; ++tt) {
      float hf = h1s[wave][tt * 16 + m16][32];
      f16x8 A = nv[tt] * splat8(hf);
      mc[tt][0] = __builtin_amdgcn_mfma_f32_16x16x32_f16(A, B0, mc[tt][0], 0, 0, 0);
      mc[tt][1] = __builtin_amdgcn_mfma_f32_16x16x32_f16(A, B1, mc[tt][1], 0, 0, 0);
    }
  }

  // dense, coalesced message store (sorted slot order)
  #pragma unroll
  for (int tt = 0; tt < 4; ++tt) {
    #pragma unroll
    for (int r = 0; r < 4; ++r) {
      long slot = base + tt * 16 + g4 * 4 + r;
      float* mp = msg + slot * 32;
      mp[m16]      = mc[tt][0][r];
      mp[m16 + 16] = mc[tt][1][r];
    }
  }
}

// ---------------- gather: per-node contiguous sum of msg rows ----------------
__global__ __launch_bounds__(256) void gather_kernel(
    const float* __restrict__ msg, const int* __restrict__ row_ptr,
    float* __restrict__ agg)
{
  int t = threadIdx.x;
  int g = t >> 5, c = t & 31;
  int n = blockIdx.x * 8 + g;
  if (n >= NN) return;
  int s0 = row_ptr[n], s1 = row_ptr[n + 1];
  float a0 = 0.f, a1 = 0.f, a2 = 0.f, a3 = 0.f;
  int s = s0;
  for (; s + 4 <= s1; s += 4) {
    a0 += msg[(long)s * 32 + c];
    a1 += msg[(long)(s + 1) * 32 + c];
    a2 += msg[(long)(s + 2) * 32 + c];
    a3 += msg[(long)(s + 3) * 32 + c];
  }
  for (; s < s1; ++s) a0 += msg[(long)s * 32 + c];
  agg[n * HID + c] = (a0 + a1) + (a2 + a3);
}

// ---------------- MXs[n][o:32][4]: (xz[o]+bz, xr[o]+br, xh[o]+b_in_h, 0) ----------------
__global__ __launch_bounds__(256) void mxp_kernel(
    const float* __restrict__ agg, const float* __restrict__ gk,
    const float* __restrict__ gb, float* __restrict__ MXs)
{
  int tid = blockIdx.x * 256 + threadIdx.x;
  if (tid >= NN * 128) return;
  int n = tid >> 7, rr = tid & 127, o = rr >> 2, q = rr & 3;
  float v = 0.f;
  if (q < 3) {
    int col = q * 32 + o;
    float s = gb[col];
    if (q < 2) s += gb[96 + col];
    const float* ar = agg + n * HID;
    #pragma unroll
    for (int j = 0; j < 32; ++j) s = fmaf(ar[j], gk[j * 96 + col], s);
    v = s;
  }
  MXs[tid] = v;
}

// ---------------- parallel chunked GRU scan with warmup ----------------
__global__ __launch_bounds__(64) void gru_scan(
    const float* __restrict__ MXs, const float* __restrict__ grk,
    const float* __restrict__ gb, const float* __restrict__ hs,
    float* __restrict__ out)
{
  __shared__ float lds[2 * CH * 128 + 256];
  int b = blockIdx.x;
  int start = b * CCH;
  int wstart = start - WARM; if (wstart < 0) wstart = 0;
  int nchunks = (start + CCH - wstart) / CH;
  int warmch = (start - wstart) / CH;

  int l = threadIdx.x;
  int o = l & 31;

  f16x2 Wz[16], Wr[16], Wh[16];
  #pragma unroll
  for (int j = 0; j < 16; ++j) {
    Wz[j] = pkrtz(grk[(2*j)*96 +  0 + o], grk[(2*j+1)*96 +  0 + o]);
    Wr[j] = pkrtz(grk[(2*j)*96 + 32 + o], grk[(2*j+1)*96 + 32 + o]);
    Wh[j] = pkrtz(grk[(2*j)*96 + 64 + o], grk[(2*j+1)*96 + 64 + o]);
  }
  float brh = gb[96 + 64 + o];
  float hcur = (wstart == 0) ? hs[o] : 0.f;

  const char* src = (const char*)(MXs + (size_t)wstart * 128);
  #pragma unroll
  for (int i = 0; i < 25; ++i)
    __builtin_amdgcn_global_load_lds(
        (const __attribute__((address_space(1))) void*)(src + i * 1024 + l * 16),
        (__attribute__((address_space(3))) void*)((char*)lds + i * 1024), 16, 0, 0);

  float* outp = out + (size_t)wstart * HID + o;

  for (int ck = 0; ck < nchunks; ++ck) {
    asm volatile("s_waitcnt vmcnt(0)" ::: "memory");
    if (ck + 1 < nchunks) {
      const char* s2 = src + (size_t)(ck + 1) * CH * 512;
      char* dbuf = (char*)lds + ((ck + 1) & 1) * CH * 512;
      #pragma unroll
      for (int i = 0; i < 25; ++i)
        __builtin_amdgcn_global_load_lds(
            (const __attribute__((address_space(1))) void*)(s2 + i * 1024 + l * 16),
            (__attribute__((address_space(3))) void*)(dbuf + i * 1024), 16, 0, 0);
    }
    const float* buf = lds + (ck & 1) * CH * 128;
    bool wr = (ck >= warmch);

    float4 mx   = *(const float4*)(buf + o * 4);
    float4 mx_n = *(const float4*)(buf + 128 + o * 4);

    #pragma unroll 2
    for (int s = 0; s < CH; ++s) {
      float4 mx_nn = *(const float4*)(buf + (s + 2) * 128 + o * 4);

      int hb = __float_as_int(hcur);
      int nb = __builtin_amdgcn_update_dpp(hb, hb, 0xB1, 0xF, 0xF, true);
      f16x2 pk = pkrtz(__int_as_float(nb), hcur);
      int pki;
      __builtin_memcpy(&pki, &pk, 4);

      float za0 = mx.x, za1 = 0.f, za2 = 0.f, za3 = 0.f;
      float ra0 = mx.y, ra1 = 0.f, ra2 = 0.f, ra3 = 0.f;
      float ha0 = brh,  ha1 = 0.f, ha2 = 0.f, ha3 = 0.f;
      #pragma unroll
      for (int j = 0; j < 16; j += 4) {
        int s0 = __builtin_amdgcn_readlane(pki, 2*j + 1);
        int s1 = __builtin_amdgcn_readlane(pki, 2*j + 3);
        int s2 = __builtin_amdgcn_readlane(pki, 2*j + 5);
        int s3 = __builtin_amdgcn_readlane(pki, 2*j + 7);
        f16x2 p0, p1, p2, p3;
        __builtin_memcpy(&p0, &s0, 4); __builtin_memcpy(&p1, &s1, 4);
        __builtin_memcpy(&p2, &s2, 4); __builtin_memcpy(&p3, &s3, 4);
        za0 = __builtin_amdgcn_fdot2(p0, Wz[j],   za0, false);
        za1 = __builtin_amdgcn_fdot2(p1, Wz[j+1], za1, false);
        za2 = __builtin_amdgcn_fdot2(p2, Wz[j+2], za2, false);
        za3 = __builtin_amdgcn_fdot2(p3, Wz[j+3], za3, false);
        ra0 = __builtin_amdgcn_fdot2(p0, Wr[j],   ra0, false);
        ra1 = __builtin_amdgcn_fdot2(p1, Wr[j+1], ra1, false);
        ra2 = __builtin_amdgcn_fdot2(p2, Wr[j+2], ra2, false);
        ra3 = __builtin_amdgcn_fdot2(p3, Wr[j+3], ra3, false);
        ha0 = __builtin_amdgcn_fdot2(p0, Wh[j],   ha0, false);
        ha1 = __builtin_amdgcn_fdot2(p1, Wh[j+1], ha1, false);
        ha2 = __builtin_amdgcn_fdot2(p2, Wh[j+2], ha2, false);
        ha3 = __builtin_amdgcn_fdot2(p3, Wh[j+3], ha3, false);
      }
      float tz = (za0 + za1) + (za2 + za3);
      float tr = (ra0 + ra1) + (ra2 + ra3);
      float yh = (ha0 + ha1) + (ha2 + ha3);

      float z = __builtin_amdgcn_rcpf(1.f + __builtin_amdgcn_exp2f(-1.442695041f * tz));
      float r = __builtin_amdgcn_rcpf(1.f + __builtin_amdgcn_exp2f(-1.442695041f * tr));

      float pre = fmaf(r, yh, mx.z);
      float e2 = __builtin_amdgcn_exp2f(pre * 2.885390082f);
      float th = fmaf(-2.f, __builtin_amdgcn_rcpf(e2 + 1.f), 1.f);

      float hn = fmaf(z, hcur - th, th);
      if (wr) outp[s * HID] = hn;
      hcur = hn;
      mx = mx_n; mx_n = mx_nn;
    }
    outp += CH * HID;
  }
  if (b == NBLK - 1) out[NN * HID + o] = hcur;
}

extern "C" void kernel_launch(void* const* d_in, const int* in_sizes, int n_in,
                              void* d_out, int out_size, void* d_ws, size_t ws_size,
                              hipStream_t stream) {
  const float* x   = (const float*)d_in[0];
  const int*   ei  = (const int*)d_in[1];
  const float* ea  = (const float*)d_in[2];
  const float* hs  = (const float*)d_in[3];
  const float* w1  = (const float*)d_in[4];
  const float* b1  = (const float*)d_in[5];
  const float* w2  = (const float*)d_in[6];
  const float* b2  = (const float*)d_in[7];
  const float* gk  = (const float*)d_in[8];
  const float* grk = (const float*)d_in[9];
  const float* gb  = (const float*)d_in[10];
  float* out = (float*)d_out;

  char* ws = (char*)d_ws;
  float* agg     = (float*)ws;                          // 1.28 MB
  float* MXs     = (float*)(ws + 1280000);              // 5.12 MB
  f16*   Wf      = (f16*)(ws + 6400000);                // 67.6 KB
  f16*   W1f     = (f16*)(ws + 6467584);                // 8 KB
  int*   cnt     = (int*)(ws + 6475776);                // 40 KB
  int*   row_ptr = (int*)(ws + 6515776);                // 40 KB + 4
  int*   ofs     = (int*)(ws + 6555840);                // 40 KB
  int*   eid     = (int*)(ws + 6595840);                // 2.56 MB
  float* msg     = (float*)(ws + 9155840);              // 81.9 MB

  prep_kernel<<<dim3(132), dim3(256), 0, stream>>>(w1, w2, b2, cnt, Wf, W1f);
  hist_kernel<<<dim3(2500), dim3(256), 0, stream>>>(ei, cnt);
  scan_kernel<<<dim3(1), dim3(256), 0, stream>>>(cnt, row_ptr, ofs);
  fill_kernel<<<dim3(2500), dim3(256), 0, stream>>>(ei, ofs, eid);
  edges_kernel<<<dim3(E_EDGES / 256), dim3(256), 0, stream>>>(x, ei, ea, b1, Wf, W1f, eid, msg);
  gather_kernel<<<dim3(1250), dim3(256), 0, stream>>>(msg, row_ptr, agg);
  mxp_kernel<<<dim3((NN * 128 + 255) / 256), dim3(256), 0, stream>>>(agg, gk, gb, MXs);
  gru_scan<<<dim3(NBLK), dim3(64), 0, stream>>>(MXs, grk, gb, hs, out);
}

// Round 12
// 194.965 us; speedup vs baseline: 1.5898x; 1.5898x over previous
//
#include <hip/hip_runtime.h>

#define E_EDGES 640000
#define NN 10000
#define HID 32
#define EDIM 128
#define CH 50      // GRU steps per LDS chunk
#define CCH 50     // output steps per scan block
#define WARM 100   // warmup steps (multiple of CH)
#define NBLK 200   // NN / CCH

typedef _Float16 f16;
typedef _Float16 f16x8 __attribute__((ext_vector_type(8)));
typedef _Float16 f16x2 __attribute__((ext_vector_type(2)));
typedef float f32x4 __attribute__((ext_vector_type(4)));

static __device__ __forceinline__ f16x2 pkrtz(float a, float b) {
  auto t = __builtin_amdgcn_cvt_pkrtz(a, b);
  f16x2 r;
  __builtin_memcpy(&r, &t, 4);
  return r;
}

static __device__ __forceinline__ f16x8 cvt8(float4 a, float4 b) {
  auto p0 = __builtin_amdgcn_cvt_pkrtz(a.x, a.y);
  auto p1 = __builtin_amdgcn_cvt_pkrtz(a.z, a.w);
  auto p2 = __builtin_amdgcn_cvt_pkrtz(b.x, b.y);
  auto p3 = __builtin_amdgcn_cvt_pkrtz(b.z, b.w);
  f16x8 r;
  __builtin_memcpy((char*)&r,      &p0, 4);
  __builtin_memcpy((char*)&r + 4,  &p1, 4);
  __builtin_memcpy((char*)&r + 8,  &p2, 4);
  __builtin_memcpy((char*)&r + 12, &p3, 4);
  return r;
}

// vector-typed variant for nontemporal loads
static __device__ __forceinline__ f16x8 cvt8v(f32x4 a, f32x4 b) {
  auto p0 = __builtin_amdgcn_cvt_pkrtz(a[0], a[1]);
  auto p1 = __builtin_amdgcn_cvt_pkrtz(a[2], a[3]);
  auto p2 = __builtin_amdgcn_cvt_pkrtz(b[0], b[1]);
  auto p3 = __builtin_amdgcn_cvt_pkrtz(b[2], b[3]);
  f16x8 r;
  __builtin_memcpy((char*)&r,      &p0, 4);
  __builtin_memcpy((char*)&r + 4,  &p1, 4);
  __builtin_memcpy((char*)&r + 8,  &p2, 4);
  __builtin_memcpy((char*)&r + 12, &p3, 4);
  return r;
}

static __device__ __forceinline__ f16x8 splat8(float h) {
  auto p = __builtin_amdgcn_cvt_pkrtz(h, h);
  int si;
  __builtin_memcpy(&si, &p, 4);
  int v[4] = {si, si, si, si};
  f16x8 r;
  __builtin_memcpy(&r, v, 16);
  return r;
}

// ---------------- prep: zero agg, build f16 fragment-ordered weights ----------------
__global__ __launch_bounds__(256) void prep_kernel(
    const float* __restrict__ w1, const float* __restrict__ w2,
    const float* __restrict__ b2, float* __restrict__ agg,
    f16* __restrict__ Wf, f16* __restrict__ W1f)
{
  int tid = blockIdx.x * 256 + threadIdx.x;
  if (tid < NN * HID) agg[tid] = 0.f;
  if (tid < 33 * 1024) {
    int r = tid & 7, l = (tid >> 3) & 63, h = (tid >> 9) & 1, c2 = tid >> 10;
    int i = (l & 15) + 16 * h, j = (l >> 4) * 8 + r;
    float v = (c2 < 32) ? w2[c2 * 1024 + i * 32 + j] : b2[i * 32 + j];
    Wf[tid] = (f16)v;
  }
  if (tid < 4 * 1024) {
    int r = tid & 7, l = (tid >> 3) & 63, h = (tid >> 9) & 1, c = tid >> 10;
    int d = c * 32 + (l >> 4) * 8 + r, k = (l & 15) + 16 * h;
    W1f[tid] = (f16)w1[d * 32 + k];
  }
}

// ---------------- edges: 64 edges/wave, atomics, nt ea loads, forced 4 waves/SIMD ----------------
__global__ __launch_bounds__(256, 4) void edges_kernel(
    const float* __restrict__ x, const int* __restrict__ ei,
    const float* __restrict__ ea, const float* __restrict__ b1,
    const f16* __restrict__ Wf, const f16* __restrict__ W1f,
    float* __restrict__ agg)
{
  __shared__ float h1s[4][64][36];   // stride 36: 16B-aligned rows
  int t = threadIdx.x;
  int wave = t >> 6, l = t & 63;
  int e0 = (blockIdx.x * 4 + wave) * 64;
  const int* colp = ei + E_EDGES;
  int m16 = l & 15, g4 = l >> 4;

  // direct per-lane x gather (x is L2/L3-resident)
  f16x8 nv[4];
  #pragma unroll
  for (int tt = 0; tt < 4; ++tt) {
    int c = colp[e0 + tt * 16 + m16];
    const float* xr = x + (long)c * HID + g4 * 8;
    nv[tt] = cvt8(*(const float4*)xr, *(const float4*)(xr + 4));
  }

  // GEMM1: h1[64e x 32k] = relu(EA @ W1 + b1); ea streamed non-temporally
  f32x4 acc[4][2];
  #pragma unroll
  for (int tt = 0; tt < 4; ++tt) { acc[tt][0] = {0.f,0.f,0.f,0.f}; acc[tt][1] = {0.f,0.f,0.f,0.f}; }
  #pragma unroll
  for (int c = 0; c < 4; ++c) {
    f16x8 A[4];
    #pragma unroll
    for (int tt = 0; tt < 4; ++tt) {
      const f32x4* eb = (const f32x4*)(ea + (long)(e0 + tt * 16 + m16) * EDIM + g4 * 8 + c * 32);
      f32x4 va = __builtin_nontemporal_load(eb);
      f32x4 vb = __builtin_nontemporal_load(eb + 1);
      A[tt] = cvt8v(va, vb);
    }
    f16x8 b0  = *(const f16x8*)(W1f + ((c * 2 + 0) * 64 + l) * 8);
    f16x8 b1v = *(const f16x8*)(W1f + ((c * 2 + 1) * 64 + l) * 8);
    #pragma unroll
    for (int tt = 0; tt < 4; ++tt) {
      acc[tt][0] = __builtin_amdgcn_mfma_f32_16x16x32_f16(A[tt], b0,  acc[tt][0], 0, 0, 0);
      acc[tt][1] = __builtin_amdgcn_mfma_f32_16x16x32_f16(A[tt], b1v, acc[tt][1], 0, 0, 0);
    }
  }
  float bb0 = b1[m16], bb1 = b1[m16 + 16];
  #pragma unroll
  for (int tt = 0; tt < 4; ++tt) {
    #pragma unroll
    for (int r = 0; r < 4; ++r) {
      h1s[wave][tt * 16 + g4 * 4 + r][m16]      = fmaxf(acc[tt][0][r] + bb0, 0.f);
      h1s[wave][tt * 16 + g4 * 4 + r][m16 + 16] = fmaxf(acc[tt][1][r] + bb1, 0.f);
    }
  }
  if (m16 == 0) {
    #pragma unroll
    for (int tt = 0; tt < 4; ++tt)
      #pragma unroll
      for (int r = 0; r < 4; ++r) h1s[wave][tt * 16 + g4 * 4 + r][32] = 1.f;
  }
  asm volatile("s_waitcnt lgkmcnt(0)" ::: "memory");   // LDS wave-private, no block barrier

  // GEMM2: messages[64e x 32i] = Z @ W; B-read amortized over 4 sub-tiles
  f32x4 mc[4][2];
  #pragma unroll
  for (int tt = 0; tt < 4; ++tt) { mc[tt][0] = {0.f,0.f,0.f,0.f}; mc[tt][1] = {0.f,0.f,0.f,0.f}; }

  #pragma unroll
  for (int cb = 0; cb < 8; ++cb) {
    float4 hv[4];
    #pragma unroll
    for (int tt = 0; tt < 4; ++tt)
      hv[tt] = *(const float4*)(&h1s[wave][tt * 16 + m16][cb * 4]);
    #pragma unroll
    for (int q = 0; q < 4; ++q) {
      int c2 = cb * 4 + q;
      f16x8 B0 = *(const f16x8*)(Wf + ((c2 * 2 + 0) * 64 + l) * 8);
      f16x8 B1 = *(const f16x8*)(Wf + ((c2 * 2 + 1) * 64 + l) * 8);
      #pragma unroll
      for (int tt = 0; tt < 4; ++tt) {
        float hf = (q == 0) ? hv[tt].x : (q == 1) ? hv[tt].y : (q == 2) ? hv[tt].z : hv[tt].w;
        f16x8 A = nv[tt] * splat8(hf);
        mc[tt][0] = __builtin_amdgcn_mfma_f32_16x16x32_f16(A, B0, mc[tt][0], 0, 0, 0);
        mc[tt][1] = __builtin_amdgcn_mfma_f32_16x16x32_f16(A, B1, mc[tt][1], 0, 0, 0);
      }
    }
  }
  { // c2 = 32: ones-row (b2 folded into Wf)
    f16x8 B0 = *(const f16x8*)(Wf + ((32 * 2 + 0) * 64 + l) * 8);
    f16x8 B1 = *(const f16x8*)(Wf + ((32 * 2 + 1) * 64 + l) * 8);
    #pragma unroll
    for (int tt = 0; tt < 4; ++tt) {
      float hf = h1s[wave][tt * 16 + m16][32];
      f16x8 A = nv[tt] * splat8(hf);
      mc[tt][0] = __builtin_amdgcn_mfma_f32_16x16x32_f16(A, B0, mc[tt][0], 0, 0, 0);
      mc[tt][1] = __builtin_amdgcn_mfma_f32_16x16x32_f16(A, B1, mc[tt][1], 0, 0, 0);
    }
  }

  // scatter-add
  const int* rowp = ei;
  #pragma unroll
  for (int tt = 0; tt < 4; ++tt) {
    #pragma unroll
    for (int r = 0; r < 4; ++r) {
      int er = rowp[e0 + tt * 16 + g4 * 4 + r];
      atomicAdd(&agg[er * HID + m16],      mc[tt][0][r]);
      atomicAdd(&agg[er * HID + m16 + 16], mc[tt][1][r]);
    }
  }
}

// ---------------- MXs[n][o:32][4]: (xz[o]+bz, xr[o]+br, xh[o]+b_in_h, 0) ----------------
__global__ __launch_bounds__(256) void mxp_kernel(
    const float* __restrict__ agg, const float* __restrict__ gk,
    const float* __restrict__ gb, float* __restrict__ MXs)
{
  int tid = blockIdx.x * 256 + threadIdx.x;
  if (tid >= NN * 128) return;
  int n = tid >> 7, rr = tid & 127, o = rr >> 2, q = rr & 3;
  float v = 0.f;
  if (q < 3) {
    int col = q * 32 + o;
    float s = gb[col];
    if (q < 2) s += gb[96 + col];
    const float* ar = agg + n * HID;
    #pragma unroll
    for (int j = 0; j < 32; ++j) s = fmaf(ar[j], gk[j * 96 + col], s);
    v = s;
  }
  MXs[tid] = v;
}

// ---------------- parallel chunked GRU scan with warmup ----------------
__global__ __launch_bounds__(64) void gru_scan(
    const float* __restrict__ MXs, const float* __restrict__ grk,
    const float* __restrict__ gb, const float* __restrict__ hs,
    float* __restrict__ out)
{
  __shared__ float lds[2 * CH * 128 + 256];
  int b = blockIdx.x;
  int start = b * CCH;
  int wstart = start - WARM; if (wstart < 0) wstart = 0;
  int nchunks = (start + CCH - wstart) / CH;
  int warmch = (start - wstart) / CH;

  int l = threadIdx.x;
  int o = l & 31;

  f16x2 Wz[16], Wr[16], Wh[16];
  #pragma unroll
  for (int j = 0; j < 16; ++j) {
    Wz[j] = pkrtz(grk[(2*j)*96 +  0 + o], grk[(2*j+1)*96 +  0 + o]);
    Wr[j] = pkrtz(grk[(2*j)*96 + 32 + o], grk[(2*j+1)*96 + 32 + o]);
    Wh[j] = pkrtz(grk[(2*j)*96 + 64 + o], grk[(2*j+1)*96 + 64 + o]);
  }
  float brh = gb[96 + 64 + o];
  float hcur = (wstart == 0) ? hs[o] : 0.f;

  const char* src = (const char*)(MXs + (size_t)wstart * 128);
  #pragma unroll
  for (int i = 0; i < 25; ++i)
    __builtin_amdgcn_global_load_lds(
        (const __attribute__((address_space(1))) void*)(src + i * 1024 + l * 16),
        (__attribute__((address_space(3))) void*)((char*)lds + i * 1024), 16, 0, 0);

  float* outp = out + (size_t)wstart * HID + o;

  for (int ck = 0; ck < nchunks; ++ck) {
    asm volatile("s_waitcnt vmcnt(0)" ::: "memory");
    if (ck + 1 < nchunks) {
      const char* s2 = src + (size_t)(ck + 1) * CH * 512;
      char* dbuf = (char*)lds + ((ck + 1) & 1) * CH * 512;
      #pragma unroll
      for (int i = 0; i < 25; ++i)
        __builtin_amdgcn_global_load_lds(
            (const __attribute__((address_space(1))) void*)(s2 + i * 1024 + l * 16),
            (__attribute__((address_space(3))) void*)(dbuf + i * 1024), 16, 0, 0);
    }
    const float* buf = lds + (ck & 1) * CH * 128;
    bool wr = (ck >= warmch);

    float4 mx   = *(const float4*)(buf + o * 4);
    float4 mx_n = *(const float4*)(buf + 128 + o * 4);

    #pragma unroll 2
    for (int s = 0; s < CH; ++s) {
      float4 mx_nn = *(const float4*)(buf + (s + 2) * 128 + o * 4);

      int hb = __float_as_int(hcur);
      int nb = __builtin_amdgcn_update_dpp(hb, hb, 0xB1, 0xF, 0xF, true);
      f16x2 pk = pkrtz(__int_as_float(nb), hcur);
      int pki;
      __builtin_memcpy(&pki, &pk, 4);

      float za0 = mx.x, za1 = 0.f, za2 = 0.f, za3 = 0.f;
      float ra0 = mx.y, ra1 = 0.f, ra2 = 0.f, ra3 = 0.f;
      float ha0 = brh,  ha1 = 0.f, ha2 = 0.f, ha3 = 0.f;
      #pragma unroll
      for (int j = 0; j < 16; j += 4) {
        int s0 = __builtin_amdgcn_readlane(pki, 2*j + 1);
        int s1 = __builtin_amdgcn_readlane(pki, 2*j + 3);
        int s2 = __builtin_amdgcn_readlane(pki, 2*j + 5);
        int s3 = __builtin_amdgcn_readlane(pki, 2*j + 7);
        f16x2 p0, p1, p2, p3;
        __builtin_memcpy(&p0, &s0, 4); __builtin_memcpy(&p1, &s1, 4);
        __builtin_memcpy(&p2, &s2, 4); __builtin_memcpy(&p3, &s3, 4);
        za0 = __builtin_amdgcn_fdot2(p0, Wz[j],   za0, false);
        za1 = __builtin_amdgcn_fdot2(p1, Wz[j+1], za1, false);
        za2 = __builtin_amdgcn_fdot2(p2, Wz[j+2], za2, false);
        za3 = __builtin_amdgcn_fdot2(p3, Wz[j+3], za3, false);
        ra0 = __builtin_amdgcn_fdot2(p0, Wr[j],   ra0, false);
        ra1 = __builtin_amdgcn_fdot2(p1, Wr[j+1], ra1, false);
        ra2 = __builtin_amdgcn_fdot2(p2, Wr[j+2], ra2, false);
        ra3 = __builtin_amdgcn_fdot2(p3, Wr[j+3], ra3, false);
        ha0 = __builtin_amdgcn_fdot2(p0, Wh[j],   ha0, false);
        ha1 = __builtin_amdgcn_fdot2(p1, Wh[j+1], ha1, false);
        ha2 = __builtin_amdgcn_fdot2(p2, Wh[j+2], ha2, false);
        ha3 = __builtin_amdgcn_fdot2(p3, Wh[j+3], ha3, false);
      }
      float tz = (za0 + za1) + (za2 + za3);
      float tr = (ra0 + ra1) + (ra2 + ra3);
      float yh = (ha0 + ha1) + (ha2 + ha3);

      float z = __builtin_amdgcn_rcpf(1.f + __builtin_amdgcn_exp2f(-1.442695041f * tz));
      float r = __builtin_amdgcn_rcpf(1.f + __builtin_amdgcn_exp2f(-1.442695041f * tr));

      float pre = fmaf(r, yh, mx.z);
      float e2 = __builtin_amdgcn_exp2f(pre * 2.885390082f);
      float th = fmaf(-2.f, __builtin_amdgcn_rcpf(e2 + 1.f), 1.f);

      float hn = fmaf(z, hcur - th, th);
      if (wr) outp[s * HID] = hn;
      hcur = hn;
      mx = mx_n; mx_n = mx_nn;
    }
    outp += CH * HID;
  }
  if (b == NBLK - 1) out[NN * HID + o] = hcur;
}

extern "C" void kernel_launch(void* const* d_in, const int* in_sizes, int n_in,
                              void* d_out, int out_size, void* d_ws, size_t ws_size,
                              hipStream_t stream) {
  const float* x   = (const float*)d_in[0];
  const int*   ei  = (const int*)d_in[1];
  const float* ea  = (const float*)d_in[2];
  const float* hs  = (const float*)d_in[3];
  const float* w1  = (const float*)d_in[4];
  const float* b1  = (const float*)d_in[5];
  const float* w2  = (const float*)d_in[6];
  const float* b2  = (const float*)d_in[7];
  const float* gk  = (const float*)d_in[8];
  const float* grk = (const float*)d_in[9];
  const float* gb  = (const float*)d_in[10];
  float* out = (float*)d_out;

  char* ws = (char*)d_ws;
  float* agg = (float*)ws;                                     // 320000 f32
  float* MXs = (float*)(ws + (size_t)320000 * 4);              // 1,280,000 f32
  f16*   Wf  = (f16*)(ws + (size_t)(320000 + 1280000) * 4);    // 33792 f16
  f16*   W1f = Wf + 33 * 1024;                                 // 4096 f16

  prep_kernel<<<dim3(1250), dim3(256), 0, stream>>>(w1, w2, b2, agg, Wf, W1f);
  edges_kernel<<<dim3(E_EDGES / 256), dim3(256), 0, stream>>>(x, ei, ea, b1, Wf, W1f, agg);
  mxp_kernel<<<dim3((NN * 128 + 255) / 256), dim3(256), 0, stream>>>(agg, gk, gb, MXs);
  gru_scan<<<dim3(NBLK), dim3(64), 0, stream>>>(MXs, grk, gb, hs, out);
}